// Round 15
// baseline (163.510 us; speedup 1.0000x reference)
//
#include <hip/hip_runtime.h>

// CompressibleFluidLoss: out[i] = mean_x + mean_y + (p[i]-p_prev[i])/dt,
// vp = v*p per node; means are masked scatter-means over edges at src.
//
// Round 15 (r14 base): bucket_reduce is HBM-bound (185MB @ 1.9TB/s = its
// 100us); ~100MB of that is vph gather-miss lines (4MB vph can't co-reside
// with the 67MB record stream in a 4MB per-XCD L2). Changes:
//  1. per-direction i16 fixed-point gather arrays vpx16/vpy16 (2MB each,
//     scale 2^-10): each gather touches one 2MB array -> hot set halved.
//  2. manual 2-way unroll in the record loop (lookups+rec loads, then both
//     gathers, then both LDS atomics) -> 2x memory-level parallelism
//     (VGPR=16 showed the compiler wasn't pipelining).

#define NPB      2048   // nodes per bucket
#define NPB_LOG  11
#define NBUCK_MAX 512
#define CE       4096   // edges per chunk
#define CB       1024   // chunk_sort block threads
#define EPT      4      // edges per thread
#define CCAP     4608   // record capacity per chunk region (mean 4096, +11s)
#define MAXCHUNK 2048
#define NHINT    4096
#define K_OFF    1073741824.0   // 2^30
#define QSCALE   1024.0f
#define QINV     (1.0f / 1024.0f)

typedef unsigned long long ull;

// ---------------- fast path ----------------

__global__ void node_pre_fast(const float2* __restrict__ v,
                              const float* __restrict__ p,
                              short* __restrict__ vpx16,
                              short* __restrict__ vpy16,
                              double2* __restrict__ side,
                              int* __restrict__ oflow, int N) {
    int i = blockIdx.x * blockDim.x + threadIdx.x;
    int stride = gridDim.x * blockDim.x;
    for (; i < N; i += stride) {
        float2 vi = v[i];
        float pi = p[i];
        float qx = fminf(fmaxf(rintf(vi.x * pi * QSCALE), -32768.f), 32767.f);
        float qy = fminf(fmaxf(rintf(vi.y * pi * QSCALE), -32768.f), 32767.f);
        vpx16[i] = (short)qx;
        vpy16[i] = (short)qy;
        side[i] = make_double2(0.0, 0.0);
    }
    if (blockIdx.x == 0 && threadIdx.x == 0) *oflow = 0;
}

__device__ __forceinline__ void route_rec(uint2 r, int k, size_t rb, int slot,
                                          uint2* __restrict__ recs,
                                          const float2* __restrict__ v,
                                          const float* __restrict__ p,
                                          double2* __restrict__ side,
                                          int* __restrict__ oflow) {
    if (slot < CCAP) { recs[rb + slot] = r; return; }
    // overflow (never in practice): exact packed-f64 global side accumulator
    unsigned sl = r.x & (NPB - 1u);
    bool diry = (r.x >> 11) & 1u;
    int d = (int)(r.x >> 12);
    float a = __uint_as_float(r.y);
    int s = k * NPB + (int)sl;
    float2 vd = v[d], vs = v[s];
    float pd = p[d], ps = p[s];
    float c = (diry ? vd.y * pd - vs.y * ps : vd.x * pd - vs.x * ps) / a;
    unsafeAtomicAdd(diry ? &side[s].y : &side[s].x, (double)c + K_OFF);
    atomicOr(oflow, 1);
}

__global__ __launch_bounds__(CB) void chunk_sort(
        const float2* __restrict__ ea,
        const int* __restrict__ src_idx,
        const int* __restrict__ dst_idx,
        const float2* __restrict__ v,
        const float* __restrict__ p,
        uint2* __restrict__ recs,
        unsigned short* __restrict__ off_mat,
        unsigned short* __restrict__ cnt_mat,
        double2* __restrict__ side,
        int* __restrict__ oflow,
        int nbuck, int E) {
    __shared__ uint2 stage[CCAP];        // 36 KB
    __shared__ int hist[NBUCK_MAX];      // 2 KB
    __shared__ int tl[NBUCK_MAX];        // 2 KB
    __shared__ int cur[NBUCK_MAX];       // 2 KB
    int c = blockIdx.x, t = threadIdx.x;
    int e0 = c * CE;

    uint2 R0[EPT], R1[EPT];
    int K[EPT], NR[EPT];
#pragma unroll
    for (int i = 0; i < EPT; ++i) {
        int e = e0 + i * CB + t;         // coalesced per sub-iteration
        NR[i] = 0; K[i] = 0;
        if (e < E) {
            float2 a = ea[e];
            bool mx = (a.x != 0.f);
            bool my = (a.y != 0.f);
            if (mx || my) {
                int s = src_idx[e];
                int d = dst_idx[e];
                K[i] = s >> NPB_LOG;
                unsigned sl = (unsigned)(s & (NPB - 1));
                unsigned dm = (unsigned)d << 12;
                NR[i] = (int)mx + (int)my;
                uint2 rx = make_uint2(sl | dm, __float_as_uint(a.x));
                uint2 ry = make_uint2(sl | 0x800u | dm, __float_as_uint(a.y));
                R0[i] = mx ? rx : ry;
                R1[i] = ry;
            }
        }
    }
    if (t < nbuck) hist[t] = 0;
    __syncthreads();
#pragma unroll
    for (int i = 0; i < EPT; ++i)
        if (NR[i]) atomicAdd(&hist[K[i]], NR[i]);
    __syncthreads();
    // inclusive scan hist -> tl over nbuck (<= 512)
    if (t < nbuck) tl[t] = hist[t];
    __syncthreads();
    for (int off = 1; off < NBUCK_MAX; off <<= 1) {
        int x = 0;
        if (t < nbuck && t >= off) x = tl[t - off];
        __syncthreads();
        if (t < nbuck) tl[t] += x;
        __syncthreads();
    }
    int total = tl[nbuck - 1];
    if (t < nbuck) {
        int excl = tl[t] - hist[t];
        cur[t] = excl;
        off_mat[(size_t)c * nbuck + t] = (unsigned short)excl;
        cnt_mat[(size_t)c * nbuck + t] = (unsigned short)hist[t];
    }
    __syncthreads();
    size_t rb = (size_t)c * CCAP;
    if (total <= CCAP) {
        // stage grouped by bucket, then flush linearly (coalesced)
#pragma unroll
        for (int i = 0; i < EPT; ++i)
            if (NR[i]) {
                int slot = atomicAdd(&cur[K[i]], NR[i]);
                stage[slot] = R0[i];
                if (NR[i] == 2) stage[slot + 1] = R1[i];
            }
        __syncthreads();
        for (int j = t; j < total; j += CB) recs[rb + j] = stage[j];
    } else {
        // overflow regime (never in practice)
#pragma unroll
        for (int i = 0; i < EPT; ++i)
            if (NR[i]) {
                int slot = atomicAdd(&cur[K[i]], NR[i]);
                route_rec(R0[i], K[i], rb, slot, recs, v, p, side, oflow);
                if (NR[i] == 2) route_rec(R1[i], K[i], rb, slot + 1, recs, v, p, side, oflow);
            }
    }
}

__global__ __launch_bounds__(1024) void bucket_reduce(
        const uint2* __restrict__ recs,
        const unsigned short* __restrict__ off_mat,
        const unsigned short* __restrict__ cnt_mat,
        const float2* __restrict__ v,
        const float* __restrict__ p,
        const short* __restrict__ vpx16,
        const short* __restrict__ vpy16,
        const double2* __restrict__ side,
        const int* __restrict__ oflow,
        const float* __restrict__ p_prev,
        const float* __restrict__ dt_ptr,
        float* __restrict__ out,
        int nchunk, int nbuck, int N) {
    __shared__ float2 vps[NPB];            // 16 KB (f32 source side, from v*p)
    __shared__ double2 acc[NPB];           // 32 KB packed (sum + cnt*2^30)
    __shared__ int glen[MAXCHUNK];         // 8 KB -> inclusive prefix
    __shared__ int goff[MAXCHUNK];         // 8 KB
    __shared__ unsigned short hint[NHINT]; // 8 KB: record 8j -> chunk
    __shared__ int s_of;
    int k = blockIdx.x, t = threadIdx.x;
    int g0 = k * NPB;
    for (int i = t; i < NPB; i += 1024) {
        int g = g0 + i;
        float2 vi = (g < N) ? v[g] : make_float2(0.f, 0.f);
        float pi = (g < N) ? p[g] : 0.f;
        vps[i] = make_float2(vi.x * pi, vi.y * pi);
        acc[i] = make_double2(0.0, 0.0);
    }
    if (t == 0) s_of = *oflow;
    for (int c = t; c < MAXCHUNK; c += 1024) {
        int len = 0, off = 0;
        if (c < nchunk) {
            off = __builtin_nontemporal_load(&off_mat[(size_t)c * nbuck + k]);
            int cnt = __builtin_nontemporal_load(&cnt_mat[(size_t)c * nbuck + k]);
            len = min(cnt, max(0, CCAP - off));   // clamp overflow'd tail
        }
        goff[c] = off;
        glen[c] = len;
    }
    __syncthreads();
    // inclusive scan glen over MAXCHUNK (2048) with 1024 threads
    for (int off = 1; off < MAXCHUNK; off <<= 1) {
        int i0 = t, i1 = t + 1024;
        int x0 = (i0 >= off) ? glen[i0 - off] : 0;
        int x1 = glen[i1 - off];
        __syncthreads();
        glen[i0] += x0;
        glen[i1] += x1;
        __syncthreads();
    }
    int total = glen[MAXCHUNK - 1];
    // build hint table: hint[j] = first chunk with glen[chunk] > 8j
    int nh = min((total + 7) >> 3, NHINT);
    for (int j = t; j < nh; j += 1024) {
        int target = j << 3;
        int lo = 0, hi = nchunk - 1;
        while (lo < hi) {
            int mid = (lo + hi) >> 1;
            if (glen[mid] > target) hi = mid; else lo = mid + 1;
        }
        hint[j] = (unsigned short)lo;
    }
    __syncthreads();
    const ull* recs64 = (const ull*)recs;
    // interleaved (coalesced) walk, 2-way unrolled for memory-level parallelism
    for (int idx = t; idx < total; idx += 2048) {
        int idxB = idx + 1024;
        bool hasB = idxB < total;
        // --- locate + load record A ---
        int curA = hint[idx >> 3];
        while (glen[curA] <= idx) ++curA;
        int preA = curA ? glen[curA - 1] : 0;
        ull rvA = __builtin_nontemporal_load(
            &recs64[(size_t)curA * CCAP + goff[curA] + (idx - preA)]);
        // --- locate + load record B ---
        ull rvB = 0;
        if (hasB) {
            int curB = hint[idxB >> 3];
            while (glen[curB] <= idxB) ++curB;
            int preB = curB ? glen[curB - 1] : 0;
            rvB = __builtin_nontemporal_load(
                &recs64[(size_t)curB * CCAP + goff[curB] + (idxB - preB)]);
        }
        // --- decode + gather both ---
        unsigned mA = (unsigned)rvA;
        float aA = __uint_as_float((unsigned)(rvA >> 32));
        int slA = (int)(mA & (NPB - 1u));
        bool dyA = (mA >> 11) & 1u;
        int dA = (int)(mA >> 12);
        short qA = dyA ? vpy16[dA] : vpx16[dA];   // 2B gather, 2MB array

        unsigned mB = (unsigned)rvB;
        float aB = __uint_as_float((unsigned)(rvB >> 32));
        int slB = (int)(mB & (NPB - 1u));
        bool dyB = (mB >> 11) & 1u;
        int dB = (int)(mB >> 12);
        short qB = 0;
        if (hasB) qB = dyB ? vpy16[dB] : vpx16[dB];
        // --- compute + accumulate ---
        float2 vsA = vps[slA];
        float cA = ((float)qA * QINV - (dyA ? vsA.y : vsA.x)) / aA;
        unsafeAtomicAdd(dyA ? &acc[slA].y : &acc[slA].x, (double)cA + K_OFF);
        if (hasB) {
            float2 vsB = vps[slB];
            float cB = ((float)qB * QINV - (dyB ? vsB.y : vsB.x)) / aB;
            unsafeAtomicAdd(dyB ? &acc[slB].y : &acc[slB].x, (double)cB + K_OFF);
        }
    }
    __syncthreads();
    float inv_dt = 1.0f / dt_ptr[0];
    for (int i = t; i < NPB; i += 1024) {
        int g = g0 + i;
        if (g < N) {
            double2 A = acc[i];
            if (s_of) {
                double2 S = side[g];
                A.x += S.x; A.y += S.y;
            }
            double cx = rint(A.x * (1.0 / K_OFF));
            double sx = A.x - cx * K_OFF;
            double cy = rint(A.y * (1.0 / K_OFF));
            double sy = A.y - cy * K_OFF;
            out[g] = (float)(sx / fmax(cx, 1.0)) + (float)(sy / fmax(cy, 1.0))
                   + (p[g] - p_prev[g]) * inv_dt;
        }
    }
}

// ---------------- fallback path (round-5: f64-packed atomics, 390us) -------

__global__ void fb_node_pre(const float2* __restrict__ v,
                            const float* __restrict__ p,
                            float2* __restrict__ vp,
                            double2* __restrict__ acc, int N) {
    int i = blockIdx.x * blockDim.x + threadIdx.x;
    int stride = gridDim.x * blockDim.x;
    for (; i < N; i += stride) {
        float2 vi = v[i];
        float pi = p[i];
        vp[i] = make_float2(vi.x * pi, vi.y * pi);
        acc[i] = make_double2(0.0, 0.0);
    }
}

__global__ void fb_edge_scatter(const float2* __restrict__ vp,
                                const float2* __restrict__ ea,
                                const int* __restrict__ src_idx,
                                const int* __restrict__ dst_idx,
                                double2* __restrict__ acc, int E) {
    int e = blockIdx.x * blockDim.x + threadIdx.x;
    if (e >= E) return;
    float2 a = ea[e];
    bool mx = (a.x != 0.f);
    bool my = (a.y != 0.f);
    if (!mx && !my) return;
    int s = src_idx[e];
    int d = dst_idx[e];
    float2 vs = vp[s];
    float2 vd = vp[d];
    double* basep = (double*)&acc[s];
    if (mx) unsafeAtomicAdd(basep + 0, (double)((vd.x - vs.x) / a.x) + K_OFF);
    if (my) unsafeAtomicAdd(basep + 1, (double)((vd.y - vs.y) / a.y) + K_OFF);
}

__global__ void fb_node_final(const double2* __restrict__ acc,
                              const float* __restrict__ p,
                              const float* __restrict__ p_prev,
                              const float* __restrict__ dt_ptr,
                              float* __restrict__ out, int N) {
    int i = blockIdx.x * blockDim.x + threadIdx.x;
    int stride = gridDim.x * blockDim.x;
    float inv_dt = 1.0f / dt_ptr[0];
    for (; i < N; i += stride) {
        double2 A = acc[i];
        double cx = rint(A.x * (1.0 / K_OFF));
        double sx = A.x - cx * K_OFF;
        double cy = rint(A.y * (1.0 / K_OFF));
        double sy = A.y - cy * K_OFF;
        out[i] = (float)(sx / fmax(cx, 1.0)) + (float)(sy / fmax(cy, 1.0))
               + (p[i] - p_prev[i]) * inv_dt;
    }
}

// ---------------- launch ----------------

extern "C" void kernel_launch(void* const* d_in, const int* in_sizes, int n_in,
                              void* d_out, int out_size, void* d_ws, size_t ws_size,
                              hipStream_t stream) {
    const float2* v_x    = (const float2*)d_in[0];
    const float*  p_x    = (const float*)d_in[2];
    const float*  p_prev = (const float*)d_in[3];
    const float*  dt     = (const float*)d_in[9];
    const float2* ea     = (const float2*)d_in[10];
    const int*    eidx   = (const int*)d_in[11];

    const int N = in_sizes[2];
    const int E = in_sizes[10] / 2;
    const int* src_idx = eidx;
    const int* dst_idx = eidx + E;

    const int nbuck  = (N + NPB - 1) >> NPB_LOG;
    const int nchunk = (E + CE - 1) / CE;

    // ws: vpx16 2 | vpy16 2 | side 16 | flag | off 2 | cnt 2 | recs 75.5 MB
    char* w = (char*)d_ws;
    short*   vpx16   = (short*)w;     w += (size_t)N * sizeof(short);
    short*   vpy16   = (short*)w;     w += (size_t)N * sizeof(short);
    double2* side    = (double2*)w;   w += (size_t)N * sizeof(double2);
    int*     oflow   = (int*)w;       w += 16;
    unsigned short* off_mat = (unsigned short*)w;  w += (size_t)nchunk * nbuck * sizeof(unsigned short);
    unsigned short* cnt_mat = (unsigned short*)w;  w += (size_t)nchunk * nbuck * sizeof(unsigned short);
    w = (char*)(((uintptr_t)w + 15) & ~(uintptr_t)15);
    uint2*   recs    = (uint2*)w;     w += (size_t)nchunk * CCAP * sizeof(uint2);
    size_t need_fast = (size_t)(w - (char*)d_ws);

    if (nbuck <= NBUCK_MAX && nchunk <= MAXCHUNK && N <= (1 << 20)
        && ws_size >= need_fast) {
        node_pre_fast<<<2048, 256, 0, stream>>>(v_x, p_x, vpx16, vpy16, side, oflow, N);
        chunk_sort<<<nchunk, CB, 0, stream>>>(ea, src_idx, dst_idx, v_x, p_x,
                                              recs, off_mat, cnt_mat, side,
                                              oflow, nbuck, E);
        bucket_reduce<<<nbuck, 1024, 0, stream>>>(recs, off_mat, cnt_mat,
                                                  v_x, p_x, vpx16, vpy16,
                                                  side, oflow, p_prev, dt,
                                                  (float*)d_out, nchunk, nbuck, N);
    } else {
        float2*  fvp  = (float2*)d_ws;
        double2* facc = (double2*)((char*)d_ws + (size_t)N * sizeof(float2));
        fb_node_pre<<<2048, 256, 0, stream>>>(v_x, p_x, fvp, facc, N);
        fb_edge_scatter<<<(E + 255) / 256, 256, 0, stream>>>(
            fvp, ea, src_idx, dst_idx, facc, E);
        fb_node_final<<<2048, 256, 0, stream>>>(
            facc, p_x, p_prev, dt, (float*)d_out, N);
    }
}

// Round 17
// 157.164 us; speedup vs baseline: 1.0404x; 1.0404x over previous
//
#include <hip/hip_runtime.h>
#include <hip/hip_fp16.h>

// CompressibleFluidLoss: out[i] = mean_x + mean_y + (p[i]-p_prev[i])/dt,
// vp = v*p per node; means are masked scatter-means over edges at src.
//
// Round 17 = r16 with the nontemporal-load compile fix (HIP float2 is a
// class type; cast through clang ext_vector float2 for the NT load).
//  - side accumulator (16MB zero-init/launch) replaced by a compact spill
//    list (never-path: chunk overflow is >= +11 sigma).
//  - NT loads for one-shot coalesced reads (v,p stage; p,p_prev epilogue)
//    so they stop evicting the 4MB vph gather array from per-XCD L2.
// Structure: chunk-major LDS sort (chunk_sort) -> per-bucket LDS reduce
// (bucket_reduce) with fp16 vph gathers + packed-f64 LDS accumulation.

#define NPB      2048   // nodes per bucket
#define NPB_LOG  11
#define NBUCK_MAX 512
#define CE       4096   // edges per chunk
#define CB       1024   // chunk_sort block threads
#define EPT      4      // edges per thread
#define CCAP     4608   // record capacity per chunk region (mean 4096, +11s)
#define MAXCHUNK 2048
#define NHINT    4096
#define SPILLCAP (1 << 20)
#define K_OFF    1073741824.0   // 2^30

typedef unsigned long long ull;
typedef float vfloat2 __attribute__((ext_vector_type(2)));

// ---------------- fast path ----------------

__global__ void node_pre_fast(const float2* __restrict__ v,
                              const float* __restrict__ p,
                              __half2* __restrict__ vph,
                              int* __restrict__ spill_cnt, int N) {
    int i = blockIdx.x * blockDim.x + threadIdx.x;
    int stride = gridDim.x * blockDim.x;
    for (; i < N; i += stride) {
        float2 vi = v[i];
        float pi = p[i];
        vph[i] = __float22half2_rn(make_float2(vi.x * pi, vi.y * pi));
    }
    if (blockIdx.x == 0 && threadIdx.x == 0) *spill_cnt = 0;
}

__device__ __forceinline__ void route_rec(uint2 r, int k, size_t rb, int slot,
                                          uint2* __restrict__ recs,
                                          uint4* __restrict__ spill,
                                          int* __restrict__ spill_cnt) {
    if (slot < CCAP) { recs[rb + slot] = r; return; }
    // overflow (never in practice): append to spill list for bucket_reduce
    int sp = atomicAdd(spill_cnt, 1);
    if (sp < SPILLCAP) spill[sp] = make_uint4(r.x, r.y, (unsigned)k, 0u);
}

__global__ __launch_bounds__(CB) void chunk_sort(
        const float2* __restrict__ ea,
        const int* __restrict__ src_idx,
        const int* __restrict__ dst_idx,
        uint2* __restrict__ recs,
        unsigned short* __restrict__ off_mat,
        unsigned short* __restrict__ cnt_mat,
        uint4* __restrict__ spill,
        int* __restrict__ spill_cnt,
        int nbuck, int E) {
    __shared__ uint2 stage[CCAP];        // 36 KB
    __shared__ int hist[NBUCK_MAX];      // 2 KB
    __shared__ int tl[NBUCK_MAX];        // 2 KB
    __shared__ int cur[NBUCK_MAX];       // 2 KB
    int c = blockIdx.x, t = threadIdx.x;
    int e0 = c * CE;

    uint2 R0[EPT], R1[EPT];
    int K[EPT], NR[EPT];
#pragma unroll
    for (int i = 0; i < EPT; ++i) {
        int e = e0 + i * CB + t;         // coalesced per sub-iteration
        NR[i] = 0; K[i] = 0;
        if (e < E) {
            float2 a = ea[e];
            bool mx = (a.x != 0.f);
            bool my = (a.y != 0.f);
            if (mx || my) {
                int s = src_idx[e];
                int d = dst_idx[e];
                K[i] = s >> NPB_LOG;
                unsigned sl = (unsigned)(s & (NPB - 1));
                unsigned dm = (unsigned)d << 12;
                NR[i] = (int)mx + (int)my;
                uint2 rx = make_uint2(sl | dm, __float_as_uint(a.x));
                uint2 ry = make_uint2(sl | 0x800u | dm, __float_as_uint(a.y));
                R0[i] = mx ? rx : ry;
                R1[i] = ry;
            }
        }
    }
    if (t < nbuck) hist[t] = 0;
    __syncthreads();
#pragma unroll
    for (int i = 0; i < EPT; ++i)
        if (NR[i]) atomicAdd(&hist[K[i]], NR[i]);
    __syncthreads();
    // inclusive scan hist -> tl over nbuck (<= 512)
    if (t < nbuck) tl[t] = hist[t];
    __syncthreads();
    for (int off = 1; off < NBUCK_MAX; off <<= 1) {
        int x = 0;
        if (t < nbuck && t >= off) x = tl[t - off];
        __syncthreads();
        if (t < nbuck) tl[t] += x;
        __syncthreads();
    }
    int total = tl[nbuck - 1];
    if (t < nbuck) {
        int excl = tl[t] - hist[t];
        cur[t] = excl;
        off_mat[(size_t)c * nbuck + t] = (unsigned short)excl;
        cnt_mat[(size_t)c * nbuck + t] = (unsigned short)hist[t];
    }
    __syncthreads();
    size_t rb = (size_t)c * CCAP;
    if (total <= CCAP) {
        // stage grouped by bucket, then flush linearly (coalesced)
#pragma unroll
        for (int i = 0; i < EPT; ++i)
            if (NR[i]) {
                int slot = atomicAdd(&cur[K[i]], NR[i]);
                stage[slot] = R0[i];
                if (NR[i] == 2) stage[slot + 1] = R1[i];
            }
        __syncthreads();
        for (int j = t; j < total; j += CB) recs[rb + j] = stage[j];
    } else {
        // overflow regime (never in practice)
#pragma unroll
        for (int i = 0; i < EPT; ++i)
            if (NR[i]) {
                int slot = atomicAdd(&cur[K[i]], NR[i]);
                route_rec(R0[i], K[i], rb, slot, recs, spill, spill_cnt);
                if (NR[i] == 2) route_rec(R1[i], K[i], rb, slot + 1, recs, spill, spill_cnt);
            }
    }
}

__global__ __launch_bounds__(1024) void bucket_reduce(
        const uint2* __restrict__ recs,
        const unsigned short* __restrict__ off_mat,
        const unsigned short* __restrict__ cnt_mat,
        const float2* __restrict__ v,
        const float* __restrict__ p,
        const __half2* __restrict__ vph,
        const uint4* __restrict__ spill,
        const int* __restrict__ spill_cnt,
        const float* __restrict__ p_prev,
        const float* __restrict__ dt_ptr,
        float* __restrict__ out,
        int nchunk, int nbuck, int N) {
    __shared__ float2 vps[NPB];            // 16 KB (f32 source side, from v*p)
    __shared__ double2 acc[NPB];           // 32 KB packed (sum + cnt*2^30)
    __shared__ int glen[MAXCHUNK];         // 8 KB -> inclusive prefix
    __shared__ int goff[MAXCHUNK];         // 8 KB
    __shared__ unsigned short hint[NHINT]; // 8 KB: record 8j -> chunk
    __shared__ int s_sp;
    int k = blockIdx.x, t = threadIdx.x;
    int g0 = k * NPB;
    const vfloat2* vv = (const vfloat2*)v;
    for (int i = t; i < NPB; i += 1024) {
        int g = g0 + i;
        vfloat2 vi = (g < N) ? __builtin_nontemporal_load(&vv[g]) : (vfloat2)(0.f);
        float pi = (g < N) ? __builtin_nontemporal_load(&p[g]) : 0.f;
        vps[i] = make_float2(vi.x * pi, vi.y * pi);
        acc[i] = make_double2(0.0, 0.0);
    }
    if (t == 0) s_sp = *spill_cnt;
    for (int c = t; c < MAXCHUNK; c += 1024) {
        int len = 0, off = 0;
        if (c < nchunk) {
            off = __builtin_nontemporal_load(&off_mat[(size_t)c * nbuck + k]);
            int cnt = __builtin_nontemporal_load(&cnt_mat[(size_t)c * nbuck + k]);
            len = min(cnt, max(0, CCAP - off));   // clamp overflow'd tail
        }
        goff[c] = off;
        glen[c] = len;
    }
    __syncthreads();
    // inclusive scan glen over MAXCHUNK (2048) with 1024 threads
    for (int off = 1; off < MAXCHUNK; off <<= 1) {
        int i0 = t, i1 = t + 1024;
        int x0 = (i0 >= off) ? glen[i0 - off] : 0;
        int x1 = glen[i1 - off];
        __syncthreads();
        glen[i0] += x0;
        glen[i1] += x1;
        __syncthreads();
    }
    int total = glen[MAXCHUNK - 1];
    // build hint table: hint[j] = first chunk with glen[chunk] > 8j
    int nh = min((total + 7) >> 3, NHINT);
    for (int j = t; j < nh; j += 1024) {
        int target = j << 3;
        int lo = 0, hi = nchunk - 1;
        while (lo < hi) {
            int mid = (lo + hi) >> 1;
            if (glen[mid] > target) hi = mid; else lo = mid + 1;
        }
        hint[j] = (unsigned short)lo;
    }
    __syncthreads();
    const ull* recs64 = (const ull*)recs;
    // interleaved (coalesced) record walk with O(1) chunk lookup
    for (int idx = t; idx < total; idx += 1024) {
        int cur = hint[idx >> 3];
        while (glen[cur] <= idx) ++cur;      // <= ~2 steps
        int pre = cur ? glen[cur - 1] : 0;
        ull rv = __builtin_nontemporal_load(
            &recs64[(size_t)cur * CCAP + goff[cur] + (idx - pre)]);
        unsigned m = (unsigned)rv;
        float a = __uint_as_float((unsigned)(rv >> 32));
        int sl = (int)(m & (NPB - 1u));
        bool diry = (m >> 11) & 1u;
        int d = (int)(m >> 12);
        float2 vpd = __half22float2(vph[d]);   // 4B gather; 4MB set, L2-hot
        float2 vs = vps[sl];
        float c = (diry ? vpd.y - vs.y : vpd.x - vs.x) / a;
        unsafeAtomicAdd(diry ? &acc[sl].y : &acc[sl].x, (double)c + K_OFF);
    }
    __syncthreads();
    // spill list (nonempty only in the never-hit overflow regime)
    int nsp = min(s_sp, SPILLCAP);
    for (int i = t; i < nsp; i += 1024) {
        uint4 r = spill[i];
        if ((int)r.z != k) continue;
        unsigned m = r.x;
        float a = __uint_as_float(r.y);
        int sl = (int)(m & (NPB - 1u));
        bool diry = (m >> 11) & 1u;
        int d = (int)(m >> 12);
        float2 vpd = __half22float2(vph[d]);
        float2 vs = vps[sl];
        float c = (diry ? vpd.y - vs.y : vpd.x - vs.x) / a;
        unsafeAtomicAdd(diry ? &acc[sl].y : &acc[sl].x, (double)c + K_OFF);
    }
    if (nsp) __syncthreads();
    float inv_dt = 1.0f / dt_ptr[0];
    for (int i = t; i < NPB; i += 1024) {
        int g = g0 + i;
        if (g < N) {
            double2 A = acc[i];
            double cx = rint(A.x * (1.0 / K_OFF));
            double sx = A.x - cx * K_OFF;
            double cy = rint(A.y * (1.0 / K_OFF));
            double sy = A.y - cy * K_OFF;
            float pd = __builtin_nontemporal_load(&p[g]);
            float pp = __builtin_nontemporal_load(&p_prev[g]);
            out[g] = (float)(sx / fmax(cx, 1.0)) + (float)(sy / fmax(cy, 1.0))
                   + (pd - pp) * inv_dt;
        }
    }
}

// ---------------- fallback path (round-5: f64-packed atomics, 390us) -------

__global__ void fb_node_pre(const float2* __restrict__ v,
                            const float* __restrict__ p,
                            float2* __restrict__ vp,
                            double2* __restrict__ acc, int N) {
    int i = blockIdx.x * blockDim.x + threadIdx.x;
    int stride = gridDim.x * blockDim.x;
    for (; i < N; i += stride) {
        float2 vi = v[i];
        float pi = p[i];
        vp[i] = make_float2(vi.x * pi, vi.y * pi);
        acc[i] = make_double2(0.0, 0.0);
    }
}

__global__ void fb_edge_scatter(const float2* __restrict__ vp,
                                const float2* __restrict__ ea,
                                const int* __restrict__ src_idx,
                                const int* __restrict__ dst_idx,
                                double2* __restrict__ acc, int E) {
    int e = blockIdx.x * blockDim.x + threadIdx.x;
    if (e >= E) return;
    float2 a = ea[e];
    bool mx = (a.x != 0.f);
    bool my = (a.y != 0.f);
    if (!mx && !my) return;
    int s = src_idx[e];
    int d = dst_idx[e];
    float2 vs = vp[s];
    float2 vd = vp[d];
    double* basep = (double*)&acc[s];
    if (mx) unsafeAtomicAdd(basep + 0, (double)((vd.x - vs.x) / a.x) + K_OFF);
    if (my) unsafeAtomicAdd(basep + 1, (double)((vd.y - vs.y) / a.y) + K_OFF);
}

__global__ void fb_node_final(const double2* __restrict__ acc,
                              const float* __restrict__ p,
                              const float* __restrict__ p_prev,
                              const float* __restrict__ dt_ptr,
                              float* __restrict__ out, int N) {
    int i = blockIdx.x * blockDim.x + threadIdx.x;
    int stride = gridDim.x * blockDim.x;
    float inv_dt = 1.0f / dt_ptr[0];
    for (; i < N; i += stride) {
        double2 A = acc[i];
        double cx = rint(A.x * (1.0 / K_OFF));
        double sx = A.x - cx * K_OFF;
        double cy = rint(A.y * (1.0 / K_OFF));
        double sy = A.y - cy * K_OFF;
        out[i] = (float)(sx / fmax(cx, 1.0)) + (float)(sy / fmax(cy, 1.0))
               + (p[i] - p_prev[i]) * inv_dt;
    }
}

// ---------------- launch ----------------

extern "C" void kernel_launch(void* const* d_in, const int* in_sizes, int n_in,
                              void* d_out, int out_size, void* d_ws, size_t ws_size,
                              hipStream_t stream) {
    const float2* v_x    = (const float2*)d_in[0];
    const float*  p_x    = (const float*)d_in[2];
    const float*  p_prev = (const float*)d_in[3];
    const float*  dt     = (const float*)d_in[9];
    const float2* ea     = (const float2*)d_in[10];
    const int*    eidx   = (const int*)d_in[11];

    const int N = in_sizes[2];
    const int E = in_sizes[10] / 2;
    const int* src_idx = eidx;
    const int* dst_idx = eidx + E;

    const int nbuck  = (N + NPB - 1) >> NPB_LOG;
    const int nchunk = (E + CE - 1) / CE;

    // ws: vph 4 | cnt_flag | off 2 | cnt 2 | spill 16 | recs 75.5 MB (~100MB)
    char* w = (char*)d_ws;
    __half2* vph      = (__half2*)w;  w += (size_t)N * sizeof(__half2);
    int*     spill_cnt= (int*)w;      w += 16;
    unsigned short* off_mat = (unsigned short*)w;  w += (size_t)nchunk * nbuck * sizeof(unsigned short);
    unsigned short* cnt_mat = (unsigned short*)w;  w += (size_t)nchunk * nbuck * sizeof(unsigned short);
    w = (char*)(((uintptr_t)w + 15) & ~(uintptr_t)15);
    uint4*   spill    = (uint4*)w;    w += (size_t)SPILLCAP * sizeof(uint4);
    uint2*   recs     = (uint2*)w;    w += (size_t)nchunk * CCAP * sizeof(uint2);
    size_t need_fast = (size_t)(w - (char*)d_ws);

    if (nbuck <= NBUCK_MAX && nchunk <= MAXCHUNK && N <= (1 << 20)
        && ws_size >= need_fast) {
        node_pre_fast<<<2048, 256, 0, stream>>>(v_x, p_x, vph, spill_cnt, N);
        chunk_sort<<<nchunk, CB, 0, stream>>>(ea, src_idx, dst_idx,
                                              recs, off_mat, cnt_mat,
                                              spill, spill_cnt, nbuck, E);
        bucket_reduce<<<nbuck, 1024, 0, stream>>>(recs, off_mat, cnt_mat,
                                                  v_x, p_x, vph,
                                                  spill, spill_cnt,
                                                  p_prev, dt,
                                                  (float*)d_out, nchunk, nbuck, N);
    } else {
        float2*  fvp  = (float2*)d_ws;
        double2* facc = (double2*)((char*)d_ws + (size_t)N * sizeof(float2));
        fb_node_pre<<<2048, 256, 0, stream>>>(v_x, p_x, fvp, facc, N);
        fb_edge_scatter<<<(E + 255) / 256, 256, 0, stream>>>(
            fvp, ea, src_idx, dst_idx, facc, E);
        fb_node_final<<<2048, 256, 0, stream>>>(
            facc, p_x, p_prev, dt, (float*)d_out, N);
    }
}

// Round 18
// 131.232 us; speedup vs baseline: 1.2460x; 1.1976x over previous
//
#include <hip/hip_runtime.h>
#include <hip/hip_fp16.h>

// CompressibleFluidLoss: out[i] = mean_x + mean_y + (p[i]-p_prev[i])/dt,
// vp = v*p per node; means are masked scatter-means over edges at src.
//
// Round 18: merged per-EDGE records (12B: meta = s_local|d<<11, ax, ay;
// masks implicit in ax!=0 / ay!=0). Both-mask edges (25%) previously made
// 2 records + 2 gathers of the SAME vph[d]; merging cuts records and
// random gathers 8.4M -> 6.3M (-25%). a stays f32 (no precision change).
// Structure otherwise r14/r17: chunk-major LDS sort -> per-bucket LDS
// reduce with fp16 vph gathers + packed-f64 LDS accumulation.

#define NPB      2048   // nodes per bucket
#define NPB_LOG  11
#define NBUCK_MAX 512
#define CE       4096   // edges per chunk
#define CB       1024   // chunk_sort block threads
#define EPT      4      // edges per thread
#define CCAP     3456   // record cap per chunk (mean 3072, +13.9 sigma)
#define MAXCHUNK 2048
#define NHINT    4096
#define SPILLCAP (1 << 18)
#define K_OFF    1073741824.0   // 2^30

typedef unsigned long long ull;

struct __align__(4) Rec12 { unsigned m; float ax, ay; };   // 12 bytes

// ---------------- fast path ----------------

__global__ void node_pre_fast(const float2* __restrict__ v,
                              const float* __restrict__ p,
                              __half2* __restrict__ vph,
                              int* __restrict__ spill_cnt, int N) {
    int i = blockIdx.x * blockDim.x + threadIdx.x;
    int stride = gridDim.x * blockDim.x;
    for (; i < N; i += stride) {
        float2 vi = v[i];
        float pi = p[i];
        vph[i] = __float22half2_rn(make_float2(vi.x * pi, vi.y * pi));
    }
    if (blockIdx.x == 0 && threadIdx.x == 0) *spill_cnt = 0;
}

__global__ __launch_bounds__(CB) void chunk_sort(
        const float2* __restrict__ ea,
        const int* __restrict__ src_idx,
        const int* __restrict__ dst_idx,
        Rec12* __restrict__ recs,
        unsigned short* __restrict__ off_mat,
        unsigned short* __restrict__ cnt_mat,
        uint4* __restrict__ spill,
        int* __restrict__ spill_cnt,
        int nbuck, int E) {
    __shared__ Rec12 stage[CCAP];        // 41.5 KB
    __shared__ int hist[NBUCK_MAX];      // 2 KB
    __shared__ int tl[NBUCK_MAX];        // 2 KB
    __shared__ int cur[NBUCK_MAX];       // 2 KB
    int c = blockIdx.x, t = threadIdx.x;
    int e0 = c * CE;

    unsigned M[EPT];
    float AX[EPT], AY[EPT];
    int K[EPT], NR[EPT];
#pragma unroll
    for (int i = 0; i < EPT; ++i) {
        int e = e0 + i * CB + t;         // coalesced per sub-iteration
        NR[i] = 0; K[i] = 0;
        if (e < E) {
            float2 a = ea[e];
            if (a.x != 0.f || a.y != 0.f) {
                int s = src_idx[e];
                int d = dst_idx[e];
                K[i] = s >> NPB_LOG;
                M[i] = (unsigned)(s & (NPB - 1)) | ((unsigned)d << NPB_LOG);
                AX[i] = a.x;
                AY[i] = a.y;
                NR[i] = 1;
            }
        }
    }
    if (t < nbuck) hist[t] = 0;
    __syncthreads();
#pragma unroll
    for (int i = 0; i < EPT; ++i)
        if (NR[i]) atomicAdd(&hist[K[i]], 1);
    __syncthreads();
    // inclusive scan hist -> tl over nbuck (<= 512)
    if (t < nbuck) tl[t] = hist[t];
    __syncthreads();
    for (int off = 1; off < NBUCK_MAX; off <<= 1) {
        int x = 0;
        if (t < nbuck && t >= off) x = tl[t - off];
        __syncthreads();
        if (t < nbuck) tl[t] += x;
        __syncthreads();
    }
    int total = tl[nbuck - 1];
    if (t < nbuck) {
        int excl = tl[t] - hist[t];
        cur[t] = excl;
        off_mat[(size_t)c * nbuck + t] = (unsigned short)excl;
        cnt_mat[(size_t)c * nbuck + t] = (unsigned short)hist[t];
    }
    __syncthreads();
    size_t rb = (size_t)c * CCAP;
    if (total <= CCAP) {
        // stage grouped by bucket, then flush linearly (coalesced)
#pragma unroll
        for (int i = 0; i < EPT; ++i)
            if (NR[i]) {
                int slot = atomicAdd(&cur[K[i]], 1);
                stage[slot].m = M[i];
                stage[slot].ax = AX[i];
                stage[slot].ay = AY[i];
            }
        __syncthreads();
        for (int j = t; j < total; j += CB) recs[rb + j] = stage[j];
    } else {
        // overflow regime (never in practice): spill list
#pragma unroll
        for (int i = 0; i < EPT; ++i)
            if (NR[i]) {
                int slot = atomicAdd(&cur[K[i]], 1);
                if (slot < CCAP) {
                    recs[rb + slot].m = M[i];
                    recs[rb + slot].ax = AX[i];
                    recs[rb + slot].ay = AY[i];
                } else {
                    int sp = atomicAdd(spill_cnt, 1);
                    if (sp < SPILLCAP)
                        spill[sp] = make_uint4(M[i], __float_as_uint(AX[i]),
                                               __float_as_uint(AY[i]), (unsigned)K[i]);
                }
            }
    }
}

__global__ __launch_bounds__(1024) void bucket_reduce(
        const Rec12* __restrict__ recs,
        const unsigned short* __restrict__ off_mat,
        const unsigned short* __restrict__ cnt_mat,
        const float2* __restrict__ v,
        const float* __restrict__ p,
        const __half2* __restrict__ vph,
        const uint4* __restrict__ spill,
        const int* __restrict__ spill_cnt,
        const float* __restrict__ p_prev,
        const float* __restrict__ dt_ptr,
        float* __restrict__ out,
        int nchunk, int nbuck, int N) {
    __shared__ float2 vps[NPB];            // 16 KB (f32 source side, from v*p)
    __shared__ double2 acc[NPB];           // 32 KB packed (sum + cnt*2^30)
    __shared__ int glen[MAXCHUNK];         // 8 KB -> inclusive prefix
    __shared__ int goff[MAXCHUNK];         // 8 KB
    __shared__ unsigned short hint[NHINT]; // 8 KB: record 8j -> chunk
    __shared__ int s_sp;
    int k = blockIdx.x, t = threadIdx.x;
    int g0 = k * NPB;
    for (int i = t; i < NPB; i += 1024) {
        int g = g0 + i;
        float2 vi = (g < N) ? v[g] : make_float2(0.f, 0.f);
        float pi = (g < N) ? p[g] : 0.f;
        vps[i] = make_float2(vi.x * pi, vi.y * pi);
        acc[i] = make_double2(0.0, 0.0);
    }
    if (t == 0) s_sp = *spill_cnt;
    for (int c = t; c < MAXCHUNK; c += 1024) {
        int len = 0, off = 0;
        if (c < nchunk) {
            off = off_mat[(size_t)c * nbuck + k];
            int cnt = cnt_mat[(size_t)c * nbuck + k];
            len = min(cnt, max(0, CCAP - off));   // clamp overflow'd tail
        }
        goff[c] = off;
        glen[c] = len;
    }
    __syncthreads();
    // inclusive scan glen over MAXCHUNK (2048) with 1024 threads
    for (int off = 1; off < MAXCHUNK; off <<= 1) {
        int i0 = t, i1 = t + 1024;
        int x0 = (i0 >= off) ? glen[i0 - off] : 0;
        int x1 = glen[i1 - off];
        __syncthreads();
        glen[i0] += x0;
        glen[i1] += x1;
        __syncthreads();
    }
    int total = glen[MAXCHUNK - 1];
    // build hint table: hint[j] = first chunk with glen[chunk] > 8j
    int nh = min((total + 7) >> 3, NHINT);
    for (int j = t; j < nh; j += 1024) {
        int target = j << 3;
        int lo = 0, hi = nchunk - 1;
        while (lo < hi) {
            int mid = (lo + hi) >> 1;
            if (glen[mid] > target) hi = mid; else lo = mid + 1;
        }
        hint[j] = (unsigned short)lo;
    }
    __syncthreads();
    // interleaved (coalesced) record walk with O(1) chunk lookup
    for (int idx = t; idx < total; idx += 1024) {
        int cur = hint[idx >> 3];
        while (glen[cur] <= idx) ++cur;      // <= ~2 steps
        int pre = cur ? glen[cur - 1] : 0;
        Rec12 r = recs[(size_t)cur * CCAP + goff[cur] + (idx - pre)];
        int sl = (int)(r.m & (NPB - 1u));
        int d = (int)(r.m >> NPB_LOG);
        float2 vpd = __half22float2(vph[d]);   // ONE gather per edge
        float2 vs = vps[sl];
        if (r.ax != 0.f)
            unsafeAtomicAdd(&acc[sl].x, (double)((vpd.x - vs.x) / r.ax) + K_OFF);
        if (r.ay != 0.f)
            unsafeAtomicAdd(&acc[sl].y, (double)((vpd.y - vs.y) / r.ay) + K_OFF);
    }
    __syncthreads();
    // spill list (nonempty only in the never-hit overflow regime)
    int nsp = min(s_sp, SPILLCAP);
    for (int i = t; i < nsp; i += 1024) {
        uint4 r = spill[i];
        if ((int)r.w != k) continue;
        int sl = (int)(r.x & (NPB - 1u));
        int d = (int)(r.x >> NPB_LOG);
        float ax = __uint_as_float(r.y);
        float ay = __uint_as_float(r.z);
        float2 vpd = __half22float2(vph[d]);
        float2 vs = vps[sl];
        if (ax != 0.f)
            unsafeAtomicAdd(&acc[sl].x, (double)((vpd.x - vs.x) / ax) + K_OFF);
        if (ay != 0.f)
            unsafeAtomicAdd(&acc[sl].y, (double)((vpd.y - vs.y) / ay) + K_OFF);
    }
    if (nsp) __syncthreads();
    float inv_dt = 1.0f / dt_ptr[0];
    for (int i = t; i < NPB; i += 1024) {
        int g = g0 + i;
        if (g < N) {
            double2 A = acc[i];
            double cx = rint(A.x * (1.0 / K_OFF));
            double sx = A.x - cx * K_OFF;
            double cy = rint(A.y * (1.0 / K_OFF));
            double sy = A.y - cy * K_OFF;
            out[g] = (float)(sx / fmax(cx, 1.0)) + (float)(sy / fmax(cy, 1.0))
                   + (p[g] - p_prev[g]) * inv_dt;
        }
    }
}

// ---------------- fallback path (round-5: f64-packed atomics, 390us) -------

__global__ void fb_node_pre(const float2* __restrict__ v,
                            const float* __restrict__ p,
                            float2* __restrict__ vp,
                            double2* __restrict__ acc, int N) {
    int i = blockIdx.x * blockDim.x + threadIdx.x;
    int stride = gridDim.x * blockDim.x;
    for (; i < N; i += stride) {
        float2 vi = v[i];
        float pi = p[i];
        vp[i] = make_float2(vi.x * pi, vi.y * pi);
        acc[i] = make_double2(0.0, 0.0);
    }
}

__global__ void fb_edge_scatter(const float2* __restrict__ vp,
                                const float2* __restrict__ ea,
                                const int* __restrict__ src_idx,
                                const int* __restrict__ dst_idx,
                                double2* __restrict__ acc, int E) {
    int e = blockIdx.x * blockDim.x + threadIdx.x;
    if (e >= E) return;
    float2 a = ea[e];
    bool mx = (a.x != 0.f);
    bool my = (a.y != 0.f);
    if (!mx && !my) return;
    int s = src_idx[e];
    int d = dst_idx[e];
    float2 vs = vp[s];
    float2 vd = vp[d];
    double* basep = (double*)&acc[s];
    if (mx) unsafeAtomicAdd(basep + 0, (double)((vd.x - vs.x) / a.x) + K_OFF);
    if (my) unsafeAtomicAdd(basep + 1, (double)((vd.y - vs.y) / a.y) + K_OFF);
}

__global__ void fb_node_final(const double2* __restrict__ acc,
                              const float* __restrict__ p,
                              const float* __restrict__ p_prev,
                              const float* __restrict__ dt_ptr,
                              float* __restrict__ out, int N) {
    int i = blockIdx.x * blockDim.x + threadIdx.x;
    int stride = gridDim.x * blockDim.x;
    float inv_dt = 1.0f / dt_ptr[0];
    for (; i < N; i += stride) {
        double2 A = acc[i];
        double cx = rint(A.x * (1.0 / K_OFF));
        double sx = A.x - cx * K_OFF;
        double cy = rint(A.y * (1.0 / K_OFF));
        double sy = A.y - cy * K_OFF;
        out[i] = (float)(sx / fmax(cx, 1.0)) + (float)(sy / fmax(cy, 1.0))
               + (p[i] - p_prev[i]) * inv_dt;
    }
}

// ---------------- launch ----------------

extern "C" void kernel_launch(void* const* d_in, const int* in_sizes, int n_in,
                              void* d_out, int out_size, void* d_ws, size_t ws_size,
                              hipStream_t stream) {
    const float2* v_x    = (const float2*)d_in[0];
    const float*  p_x    = (const float*)d_in[2];
    const float*  p_prev = (const float*)d_in[3];
    const float*  dt     = (const float*)d_in[9];
    const float2* ea     = (const float2*)d_in[10];
    const int*    eidx   = (const int*)d_in[11];

    const int N = in_sizes[2];
    const int E = in_sizes[10] / 2;
    const int* src_idx = eidx;
    const int* dst_idx = eidx + E;

    const int nbuck  = (N + NPB - 1) >> NPB_LOG;
    const int nchunk = (E + CE - 1) / CE;

    // ws: vph 4 | flag | off 2 | cnt 2 | spill 4 | recs 85 MB  (~97 MB)
    char* w = (char*)d_ws;
    __half2* vph      = (__half2*)w;  w += (size_t)N * sizeof(__half2);
    int*     spill_cnt= (int*)w;      w += 16;
    unsigned short* off_mat = (unsigned short*)w;  w += (size_t)nchunk * nbuck * sizeof(unsigned short);
    unsigned short* cnt_mat = (unsigned short*)w;  w += (size_t)nchunk * nbuck * sizeof(unsigned short);
    w = (char*)(((uintptr_t)w + 15) & ~(uintptr_t)15);
    uint4*   spill    = (uint4*)w;    w += (size_t)SPILLCAP * sizeof(uint4);
    Rec12*   recs     = (Rec12*)w;    w += (size_t)nchunk * CCAP * sizeof(Rec12);
    size_t need_fast = (size_t)(w - (char*)d_ws);

    if (nbuck <= NBUCK_MAX && nchunk <= MAXCHUNK && N <= (1 << 20)
        && ws_size >= need_fast) {
        node_pre_fast<<<2048, 256, 0, stream>>>(v_x, p_x, vph, spill_cnt, N);
        chunk_sort<<<nchunk, CB, 0, stream>>>(ea, src_idx, dst_idx,
                                              recs, off_mat, cnt_mat,
                                              spill, spill_cnt, nbuck, E);
        bucket_reduce<<<nbuck, 1024, 0, stream>>>(recs, off_mat, cnt_mat,
                                                  v_x, p_x, vph,
                                                  spill, spill_cnt,
                                                  p_prev, dt,
                                                  (float*)d_out, nchunk, nbuck, N);
    } else {
        float2*  fvp  = (float2*)d_ws;
        double2* facc = (double2*)((char*)d_ws + (size_t)N * sizeof(float2));
        fb_node_pre<<<2048, 256, 0, stream>>>(v_x, p_x, fvp, facc, N);
        fb_edge_scatter<<<(E + 255) / 256, 256, 0, stream>>>(
            fvp, ea, src_idx, dst_idx, facc, E);
        fb_node_final<<<2048, 256, 0, stream>>>(
            facc, p_x, p_prev, dt, (float*)d_out, N);
    }
}